// Round 4
// baseline (133.746 us; speedup 1.0000x reference)
//
#include <hip/hip_runtime.h>
#include <hip/hip_bf16.h>
#include <stdint.h>

// Flash attention B=4,H=8,S=2048,D=64 fp32 io, bf16 MFMA compute.
// Round 17: LDS-reuse attack. R16 (no-max softmax) = 55us with per-CU cycles
// MFMA 33K / VALU 41K / LDS-read 49K summing to ~total -> pipes serialize.
// LDS still biggest. This round: each wave takes 64 q-rows (2 groups) and
// HALF the epoch's keys (key-split wave pairs kh=0/1). Every K/V fragment
// read from LDS now feeds 2 MFMAs (both q-groups) -> ds_reads/wave-epoch
// 32 -> 16. MFMA+VALU totals unchanged; waves/grid/staging unchanged.
// No-max softmax makes the kh-merge a plain sum (no rescale): O = O0+O1,
// l = l0+l1, done once in the epilogue through LDS.

typedef __bf16 bf16;
typedef __attribute__((ext_vector_type(8))) __bf16 bf16x8;
typedef __attribute__((ext_vector_type(4))) __bf16 bf16x4;
typedef __attribute__((ext_vector_type(4))) float floatx4;
typedef __attribute__((ext_vector_type(16))) float floatx16;
typedef __attribute__((ext_vector_type(4))) int int4v;
typedef __attribute__((ext_vector_type(2))) unsigned int uint2v;

#define SLEN 2048
#define DH   64
#define BR   64
#define BC   64
#define NKT  (SLEN / BC)      // 32 64-key tiles
#define NEP  (NKT / 2)        // 16 epochs of 128 keys
#define NQT  (SLEN / BR)
#define BH_N 32
#define LOG2E 1.44269504088896341f

#define CHB_L  1024           // LDS chunk stride (8 rows x 128B, no pad)
#define IMGB_L 8192           // bytes per K or V image (8 chunks)
#define IMGE_G 4096           // bf16 elements per image in global (8192 B)
#define BUF2   (4 * IMGB_L)   // K0,V0,K1,V1 per epoch buffer (32 KB)

#define AS1 __attribute__((address_space(1)))
#define AS3 __attribute__((address_space(3)))

static __device__ inline void gload_lds16(const void* g, void* l) {
    __builtin_amdgcn_global_load_lds((const AS1 uint32_t*)g, (AS3 uint32_t*)l, 16, 0, 0);
}

static __device__ inline float fexp2(float x) {
    return __builtin_amdgcn_exp2f(x);   // raw v_exp_f32
}

static_assert(BH_N == NQT, "prep kernel folds bh and qt onto one grid axis");

// ---- prepass: kv -> swizzled K/V LDS-images + mask flags ----
// granule (chunk c, pos p, row r): content granule g = (p - r - 4*(c&1)) & 7
// K image: row = key, granule g = d's 8g..8g+7.
// V image: rows = d, content = LOGICAL keys 8g..8g+7 (identity order).
__global__ __launch_bounds__(256) void kv_prep(
    const float* __restrict__ kv, const float* __restrict__ mask,
    bf16* __restrict__ kvK, bf16* __restrict__ kvT, int* __restrict__ flags)
{
    __shared__ bf16 Tl[64 * 72];
    __shared__ int wany[4];
    const int kt = blockIdx.x, z = blockIdx.y;   // z = bh for kv, z = qt for mask
    const int t = threadIdx.x;

    float acc = 0.f;
#pragma unroll
    for (int i = 0; i < 4; ++i) {
        int f = i * 256 + t;
        int row = f >> 4, c4 = (f & 15) * 4;
        const float4 v = *(const float4*)(mask + (size_t)(z * BR + row) * SLEN + kt * BC + c4);
        acc = fmaxf(acc, fmaxf(fmaxf(fabsf(v.x), fabsf(v.y)), fmaxf(fabsf(v.z), fabsf(v.w))));
    }
    unsigned long long any = __ballot(acc != 0.f);
    if ((t & 63) == 0) wany[t >> 6] = (any != 0ull) ? 1 : 0;

    const float* src = kv + ((size_t)z * SLEN + kt * BC) * DH;
#pragma unroll
    for (int i = 0; i < 4; ++i) {
        int f = i * 256 + t;
        int key = f >> 4, d4 = (f & 15) * 4;
        float4 v = *(const float4*)(src + (size_t)key * DH + d4);
        bf16x4 b; b[0] = (bf16)v.x; b[1] = (bf16)v.y; b[2] = (bf16)v.z; b[3] = (bf16)v.w;
        *(bf16x4*)&Tl[key * 72 + d4] = b;
    }
    __syncthreads();
    if (t == 0) flags[z * NKT + kt] = wany[0] | wany[1] | wany[2] | wany[3];

    // K image
    bf16* outK = kvK + ((size_t)z * NKT + kt) * IMGE_G;
#pragma unroll
    for (int i = 0; i < 2; ++i) {
        int G = i * 256 + t;
        int c = G >> 6, L = G & 63, rl = L >> 3, p = L & 7;
        int g = (p - rl - 4 * (c & 1)) & 7, key = 8 * c + rl;
        bf16x8 w = *(const bf16x8*)&Tl[key * 72 + g * 8];
        *(bf16x8*)(outK + (size_t)G * 8) = w;
    }
    // V image: rows = d, content = logical keys 8g..8g+7 (identity gather)
    bf16* outV = kvT + ((size_t)z * NKT + kt) * IMGE_G;
#pragma unroll
    for (int i = 0; i < 2; ++i) {
        int G = i * 256 + t;
        int c = G >> 6, L = G & 63, dl = L >> 3, p = L & 7;
        int g = (p - dl - 4 * (c & 1)) & 7, d = 8 * c + dl;
        bf16x8 w;
#pragma unroll
        for (int j = 0; j < 8; ++j)
            w[j] = Tl[(8 * g + j) * 72 + d];
        *(bf16x8*)(outV + (size_t)G * 8) = w;
    }
}

// ---- main fused attention: 32x32x16 MFMA, 64 q-rows/wave, key-split ----
// 4 waves: kh = w&1 (64-key half of epoch), qh = w>>1 (64-row q half).
// Per wave: 2 q-groups (g) of 32 rows; every K/V frag read feeds both.
// S^T = K * Q^T: col = lane&31 = qrow, row = (reg&3)+8*(reg>>2)+4*(lane>>5).
// O^T = V^T * P^T: col = qrow, row = d on regs. m == 0 (no-max softmax).
// kh halves merged by plain addition in the epilogue (no rescale needed).
__global__ __launch_bounds__(256, 2) void attn_fwd17(
    const float* __restrict__ q, const float* __restrict__ mask,
    const int* __restrict__ flags,
    const bf16* __restrict__ kvK, const bf16* __restrict__ kvT,
    float* __restrict__ out)
{
    __shared__ __align__(16) char smem[2 * BUF2];   // 64 KiB (reused for merge)

    const int bh = blockIdx.x;
    const int qt = blockIdx.y;          // 128-row q tile
    const int q0 = qt * 128;
    const int t = threadIdx.x;
    const int w = t >> 6, lane = t & 63;   // wave in [0,4)
    const int kh = w & 1, qh = w >> 1;
    const int r5 = lane & 31, h = lane >> 5;
    const int c3 = r5 >> 3, rl = lane & 7;

    // Q^T B-fragments for both 32-row groups (scale folded)
    const float qscale = 0.125f * LOG2E;
    bf16x8 qf[2][4];
#pragma unroll
    for (int g = 0; g < 2; ++g) {
        const float* qrow = q + ((size_t)bh * SLEN + q0 + qh * 64 + g * 32 + r5) * DH;
#pragma unroll
        for (int s = 0; s < 4; ++s) {
            float4 f0 = *(const float4*)(qrow + 16 * s + 8 * h);
            float4 f1 = *(const float4*)(qrow + 16 * s + 8 * h + 4);
            bf16x8 a;
            a[0] = (bf16)(f0.x * qscale); a[1] = (bf16)(f0.y * qscale);
            a[2] = (bf16)(f0.z * qscale); a[3] = (bf16)(f0.w * qscale);
            a[4] = (bf16)(f1.x * qscale); a[5] = (bf16)(f1.y * qscale);
            a[6] = (bf16)(f1.z * qscale); a[7] = (bf16)(f1.w * qscale);
            qf[g][s] = a;
        }
    }

    // flag bitmask for this wave's 64-row flag tile (bit = 64-key tile index)
    const int fqt = qt * 2 + qh;
    unsigned fmask;
    {
        int ld = (lane < 32) ? flags[fqt * NKT + lane] : 0;
        fmask = (unsigned)__ballot(ld != 0);
    }

    // per-lane in-image read offsets: granule g = 2s+h of row r5
    int addr4[4];
#pragma unroll
    for (int s = 0; s < 4; ++s) {
        int slot = (2 * s + h + rl + 4 * (c3 & 1)) & 7;
        addr4[s] = c3 * 1024 + rl * 128 + slot * 16;
    }

    floatx16 o[2][2];   // [q-group][dt]
#pragma unroll
    for (int g = 0; g < 2; ++g)
#pragma unroll
        for (int dt = 0; dt < 2; ++dt)
#pragma unroll
            for (int i = 0; i < 16; ++i) o[g][dt][i] = 0.f;
    float l_run[2] = {0.f, 0.f};

    const bf16* kvKb = kvK + (size_t)bh * NKT * IMGE_G;
    const bf16* kvTb = kvT + (size_t)bh * NKT * IMGE_G;

    // stage 64-key tiles (t2, t2+1) into buffer Bn: each wave: chunks 2w,2w+1
    auto stage = [&](int t2, char* Bn) {
        const bf16* gK = kvKb + (size_t)t2 * IMGE_G;
        const bf16* gV = kvTb + (size_t)t2 * IMGE_G;
#pragma unroll
        for (int cc = 0; cc < 2; ++cc) {
            const int c = 2 * w + cc;
            gload_lds16(gK + (size_t)c * 512 + lane * 8,          Bn +              c * CHB_L);
            gload_lds16(gV + (size_t)c * 512 + lane * 8,          Bn + IMGB_L +     c * CHB_L);
            gload_lds16(gK + IMGE_G + (size_t)c * 512 + lane * 8, Bn + 2 * IMGB_L + c * CHB_L);
            gload_lds16(gV + IMGE_G + (size_t)c * 512 + lane * 8, Bn + 3 * IMGB_L + c * CHB_L);
        }
    };

    stage(0, smem);

    for (int e = 0; e < NEP; ++e) {
        __syncthreads();   // drains vmcnt -> buf[e&1] ready; prev compute done

        if (e + 1 < NEP) stage(2 * e + 2, smem + ((e + 1) & 1) * BUF2);

        const char* B    = smem + (e & 1) * BUF2;
        const char* Kimg = B + kh * (2 * IMGB_L);
        const char* Vimg = B + IMGB_L + kh * (2 * IMGB_L);
        const int   ktile = 2 * e + kh;
        const bool  domask = (fmask >> ktile) & 1u;

#pragma unroll
        for (int T = 0; T < 2; ++T) {
            // QK^T for both q-groups; each kf read feeds 2 MFMAs
            floatx16 s0, s1;
#pragma unroll
            for (int i = 0; i < 16; ++i) { s0[i] = 0.f; s1[i] = 0.f; }
#pragma unroll
            for (int ss = 0; ss < 4; ++ss) {
                bf16x8 kf = *(const bf16x8*)(Kimg + T * 4096 + addr4[ss]);
                s0 = __builtin_amdgcn_mfma_f32_32x32x16_bf16(kf, qf[0][ss], s0, 0, 0, 0);
                s1 = __builtin_amdgcn_mfma_f32_32x32x16_bf16(kf, qf[1][ss], s1, 0, 0, 0);
            }

            if (domask) {
                const float* m0 = mask + (size_t)(q0 + qh * 64 + r5) * SLEN
                                  + ktile * 64 + T * 32 + 4 * h;
                const float* m1 = m0 + (size_t)32 * SLEN;
#pragma unroll
                for (int g4 = 0; g4 < 4; ++g4) {
                    float4 a = *(const float4*)(m0 + 8 * g4);
                    float4 b = *(const float4*)(m1 + 8 * g4);
                    s0[4 * g4 + 0] += a.x * LOG2E; s0[4 * g4 + 1] += a.y * LOG2E;
                    s0[4 * g4 + 2] += a.z * LOG2E; s0[4 * g4 + 3] += a.w * LOG2E;
                    s1[4 * g4 + 0] += b.x * LOG2E; s1[4 * g4 + 1] += b.y * LOG2E;
                    s1[4 * g4 + 2] += b.z * LOG2E; s1[4 * g4 + 3] += b.w * LOG2E;
                }
            }

            // no-max softmax: p = exp2(s); fully per-lane.
            float ev0[16], ev1[16];
#pragma unroll
            for (int i = 0; i < 16; ++i) { ev0[i] = fexp2(s0[i]); ev1[i] = fexp2(s1[i]); }
            l_run[0] += ((ev0[0] + ev0[1]) + (ev0[2] + ev0[3]))
                      + ((ev0[4] + ev0[5]) + (ev0[6] + ev0[7]))
                      + ((ev0[8] + ev0[9]) + (ev0[10] + ev0[11]))
                      + ((ev0[12] + ev0[13]) + (ev0[14] + ev0[15]));
            l_run[1] += ((ev1[0] + ev1[1]) + (ev1[2] + ev1[3]))
                      + ((ev1[4] + ev1[5]) + (ev1[6] + ev1[7]))
                      + ((ev1[8] + ev1[9]) + (ev1[10] + ev1[11]))
                      + ((ev1[12] + ev1[13]) + (ev1[14] + ev1[15]));

            // pack to PV B-frags (lane h holds keys {4h+i, 8+4h+i, ...};
            // frag A = keys 8h..8h+7, frag B = 16+8h..16+8h+7 of this sub-tile)
            bf16x8 pf0A, pf0B, pf1A, pf1B;
            {
                bf16x4 lA = { (bf16)ev0[0],  (bf16)ev0[1],  (bf16)ev0[2],  (bf16)ev0[3]  };
                bf16x4 hA = { (bf16)ev0[4],  (bf16)ev0[5],  (bf16)ev0[6],  (bf16)ev0[7]  };
                bf16x4 lB = { (bf16)ev0[8],  (bf16)ev0[9],  (bf16)ev0[10], (bf16)ev0[11] };
                bf16x4 hB = { (bf16)ev0[12], (bf16)ev0[13], (bf16)ev0[14], (bf16)ev0[15] };
                uint2v xA = __builtin_bit_cast(uint2v, lA);
                uint2v yA = __builtin_bit_cast(uint2v, hA);
                uint2v xB = __builtin_bit_cast(uint2v, lB);
                uint2v yB = __builtin_bit_cast(uint2v, hB);
                uint2v sA0 = __builtin_amdgcn_permlane32_swap(xA[0], yA[0], false, false);
                uint2v sA1 = __builtin_amdgcn_permlane32_swap(xA[1], yA[1], false, false);
                uint2v sB0 = __builtin_amdgcn_permlane32_swap(xB[0], yB[0], false, false);
                uint2v sB1 = __builtin_amdgcn_permlane32_swap(xB[1], yB[1], false, false);
                int4v pAi = { (int)sA0[0], (int)sA1[0], (int)sA0[1], (int)sA1[1] };
                int4v pBi = { (int)sB0[0], (int)sB1[0], (int)sB0[1], (int)sB1[1] };
                pf0A = __builtin_bit_cast(bf16x8, pAi);
                pf0B = __builtin_bit_cast(bf16x8, pBi);
            }
            {
                bf16x4 lA = { (bf16)ev1[0],  (bf16)ev1[1],  (bf16)ev1[2],  (bf16)ev1[3]  };
                bf16x4 hA = { (bf16)ev1[4],  (bf16)ev1[5],  (bf16)ev1[6],  (bf16)ev1[7]  };
                bf16x4 lB = { (bf16)ev1[8],  (bf16)ev1[9],  (bf16)ev1[10], (bf16)ev1[11] };
                bf16x4 hB = { (bf16)ev1[12], (bf16)ev1[13], (bf16)ev1[14], (bf16)ev1[15] };
                uint2v xA = __builtin_bit_cast(uint2v, lA);
                uint2v yA = __builtin_bit_cast(uint2v, hA);
                uint2v xB = __builtin_bit_cast(uint2v, lB);
                uint2v yB = __builtin_bit_cast(uint2v, hB);
                uint2v sA0 = __builtin_amdgcn_permlane32_swap(xA[0], yA[0], false, false);
                uint2v sA1 = __builtin_amdgcn_permlane32_swap(xA[1], yA[1], false, false);
                uint2v sB0 = __builtin_amdgcn_permlane32_swap(xB[0], yB[0], false, false);
                uint2v sB1 = __builtin_amdgcn_permlane32_swap(xB[1], yB[1], false, false);
                int4v pAi = { (int)sA0[0], (int)sA1[0], (int)sA0[1], (int)sA1[1] };
                int4v pBi = { (int)sB0[0], (int)sB1[0], (int)sB0[1], (int)sB1[1] };
                pf1A = __builtin_bit_cast(bf16x8, pAi);
                pf1B = __builtin_bit_cast(bf16x8, pBi);
            }

            // O += P V for both groups; each V frag read feeds 2 MFMAs
            const int uA = 2 * T, uB = 2 * T + 1;
#pragma unroll
            for (int dt = 0; dt < 2; ++dt) {
                bf16x8 vA = *(const bf16x8*)(Vimg + dt * 4096 + addr4[uA]);
                bf16x8 vB = *(const bf16x8*)(Vimg + dt * 4096 + addr4[uB]);
                o[0][dt] = __builtin_amdgcn_mfma_f32_32x32x16_bf16(vA, pf0A, o[0][dt], 0, 0, 0);
                o[0][dt] = __builtin_amdgcn_mfma_f32_32x32x16_bf16(vB, pf0B, o[0][dt], 0, 0, 0);
                o[1][dt] = __builtin_amdgcn_mfma_f32_32x32x16_bf16(vA, pf1A, o[1][dt], 0, 0, 0);
                o[1][dt] = __builtin_amdgcn_mfma_f32_32x32x16_bf16(vB, pf1B, o[1][dt], 0, 0, 0);
            }
        }
    }

    // ---- merge kh=1 partial into kh=0 (plain sums: no-max softmax) ----
    __syncthreads();                       // all main-loop LDS reads done
    float* Obuf = (float*)smem;            // [((qh*2+g)*2+dt)*4+k][lane] float4 (32 KB)
    float* Lbuf = (float*)(smem + 32768);  // [qh*2+g][lane] float (1 KB)
    if (kh == 1) {
#pragma unroll
        for (int g = 0; g < 2; ++g) {
#pragma unroll
            for (int dt = 0; dt < 2; ++dt)
#pragma unroll
                for (int k = 0; k < 4; ++k) {
                    float4 v;
                    v.x = o[g][dt][4 * k + 0]; v.y = o[g][dt][4 * k + 1];
                    v.z = o[g][dt][4 * k + 2]; v.w = o[g][dt][4 * k + 3];
                    *(float4*)(Obuf + ((size_t)(((qh * 2 + g) * 2 + dt) * 4 + k) * 64 + lane) * 4) = v;
                }
            Lbuf[(qh * 2 + g) * 64 + lane] = l_run[g];
        }
    }
    __syncthreads();
    if (kh == 0) {
#pragma unroll
        for (int g = 0; g < 2; ++g) {
            float lsum = l_run[g] + Lbuf[(qh * 2 + g) * 64 + lane];
            float l = lsum + __shfl_xor(lsum, 32);
            float inv = 1.f / l;
            // O^T reg i -> d = 32dt + 8*(i>>2) + 4h + (i&3), qrow = lane&31
            float* ob = out + ((size_t)bh * SLEN + q0 + qh * 64 + g * 32 + r5) * DH + 4 * h;
#pragma unroll
            for (int dt = 0; dt < 2; ++dt)
#pragma unroll
                for (int k = 0; k < 4; ++k) {
                    float4 p = *(const float4*)(Obuf + ((size_t)(((qh * 2 + g) * 2 + dt) * 4 + k) * 64 + lane) * 4);
                    float4 v;
                    v.x = (o[g][dt][4 * k + 0] + p.x) * inv;
                    v.y = (o[g][dt][4 * k + 1] + p.y) * inv;
                    v.z = (o[g][dt][4 * k + 2] + p.z) * inv;
                    v.w = (o[g][dt][4 * k + 3] + p.w) * inv;
                    *(float4*)(ob + dt * 32 + 8 * k) = v;
                }
        }
    }
}

// ---- legacy fallback (round-1 kernel) if ws is too small for the prepass ----
#define LDT 72
__global__ __launch_bounds__(256) void attn_mask_flags(
    const float* __restrict__ mask, int* __restrict__ flags)
{
    const int kt = blockIdx.x, qt = blockIdx.y;
    const int t = threadIdx.x;
    float acc = 0.f;
#pragma unroll
    for (int i = 0; i < 4; ++i) {
        int f = i * 256 + t;
        int row = f >> 4, c4 = (f & 15) * 4;
        const float4 v = *(const float4*)(mask + (size_t)(qt * BR + row) * SLEN + kt * BC + c4);
        acc = fmaxf(acc, fmaxf(fmaxf(fabsf(v.x), fabsf(v.y)), fmaxf(fabsf(v.z), fabsf(v.w))));
    }
    unsigned long long any = __ballot(acc != 0.f);
    __shared__ int wany[4];
    if ((t & 63) == 0) wany[t >> 6] = (any != 0ull) ? 1 : 0;
    __syncthreads();
    if (t == 0) flags[qt * NKT + kt] = wany[0] | wany[1] | wany[2] | wany[3];
}

__global__ __launch_bounds__(256) void attn_fwd(
    const float* __restrict__ q, const float* __restrict__ kv,
    const float* __restrict__ mask, const int* __restrict__ flags,
    float* __restrict__ out)
{
    __shared__ __align__(16) bf16 Kl[BC * LDT];
    __shared__ __align__(16) bf16 Vt[DH * LDT];
    __shared__ __align__(16) bf16 Pl[BR * LDT];

    const int qt = blockIdx.x;
    const int bh = blockIdx.y;
    const int q0 = qt * BR;
    const int t = threadIdx.x;
    const int wave = t >> 6, lane = t & 63;
    const int ln16 = lane & 15, quad = lane >> 4;

    const float qscale = 0.125f * LOG2E;
    bf16x8 aq[2];
    {
        const float* qrow = q + ((size_t)bh * SLEN + q0 + wave * 16 + ln16) * DH;
#pragma unroll
        for (int kc = 0; kc < 2; ++kc) {
            float4 f0 = *(const float4*)(qrow + kc * 32 + quad * 8);
            float4 f1 = *(const float4*)(qrow + kc * 32 + quad * 8 + 4);
            bf16x8 a;
            a[0] = (bf16)(f0.x * qscale); a[1] = (bf16)(f0.y * qscale);
            a[2] = (bf16)(f0.z * qscale); a[3] = (bf16)(f0.w * qscale);
            a[4] = (bf16)(f1.x * qscale); a[5] = (bf16)(f1.y * qscale);
            a[6] = (bf16)(f1.z * qscale); a[7] = (bf16)(f1.w * qscale);
            aq[kc] = a;
        }
    }

    floatx4 o[4];
#pragma unroll
    for (int dt = 0; dt < 4; ++dt) o[dt] = (floatx4){0.f, 0.f, 0.f, 0.f};
    float m_run[4], l_run[4];
#pragma unroll
    for (int r = 0; r < 4; ++r) { m_run[r] = -3.0e38f; l_run[r] = 0.f; }

    const float* kvb = kv + (size_t)bh * SLEN * DH;

    for (int kt = 0; kt < NKT; ++kt) {
        float4 st[4];
        const float* kvt = kvb + (size_t)kt * BC * DH;
#pragma unroll
        for (int i = 0; i < 4; ++i) {
            int f = i * 256 + t;
            st[i] = *(const float4*)(kvt + (size_t)f * 4);
        }
        __syncthreads();
#pragma unroll
        for (int i = 0; i < 4; ++i) {
            int f = i * 256 + t;
            int key = f >> 4, d4 = (f & 15) * 4;
            bf16 b0 = (bf16)st[i].x, b1 = (bf16)st[i].y, b2 = (bf16)st[i].z, b3 = (bf16)st[i].w;
            *(bf16x4*)&Kl[key * LDT + d4] = (bf16x4){b0, b1, b2, b3};
            Vt[(d4 + 0) * LDT + key] = b0;
            Vt[(d4 + 1) * LDT + key] = b1;
            Vt[(d4 + 2) * LDT + key] = b2;
            Vt[(d4 + 3) * LDT + key] = b3;
        }
        __syncthreads();

        floatx4 s[4];
#pragma unroll
        for (int nt = 0; nt < 4; ++nt) {
            s[nt] = (floatx4){0.f, 0.f, 0.f, 0.f};
#pragma unroll
            for (int kc = 0; kc < 2; ++kc) {
                bf16x8 bk = *(const bf16x8*)&Kl[(ln16 + 16 * nt) * LDT + kc * 32 + quad * 8];
                s[nt] = __builtin_amdgcn_mfma_f32_16x16x32_bf16(aq[kc], bk, s[nt], 0, 0, 0);
            }
        }

        if (!flags || flags[qt * NKT + kt]) {
            const float* mrow = mask + (size_t)(q0 + quad * 4) * SLEN + kt * BC + ln16;
#pragma unroll
            for (int r = 0; r < 4; ++r)
#pragma unroll
                for (int nt = 0; nt < 4; ++nt)
                    s[nt][r] += mrow[(size_t)r * SLEN + nt * 16] * LOG2E;
        }

#pragma unroll
        for (int r = 0; r < 4; ++r) {
            float mx = fmaxf(fmaxf(s[0][r], s[1][r]), fmaxf(s[2][r], s[3][r]));
            mx = fmaxf(mx, __shfl_xor(mx, 1));
            mx = fmaxf(mx, __shfl_xor(mx, 2));
            mx = fmaxf(mx, __shfl_xor(mx, 4));
            mx = fmaxf(mx, __shfl_xor(mx, 8));
            float mnew = fmaxf(m_run[r], mx);
            float alpha = exp2f(m_run[r] - mnew);
            m_run[r] = mnew;
            float rs = 0.f;
#pragma unroll
            for (int nt = 0; nt < 4; ++nt) {
                float p = exp2f(s[nt][r] - mnew);
                s[nt][r] = p;
                rs += p;
            }
            rs += __shfl_xor(rs, 1);
            rs += __shfl_xor(rs, 2);
            rs += __shfl_xor(rs, 4);
            rs += __shfl_xor(rs, 8);
            l_run[r] = l_run[r] * alpha + rs;
#pragma unroll
            for (int dt = 0; dt < 4; ++dt) o[dt][r] *= alpha;
        }

#pragma unroll
        for (int nt = 0; nt < 4; ++nt)
#pragma unroll
            for (int r = 0; r < 4; ++r)
                Pl[(wave * 16 + quad * 4 + r) * LDT + ln16 + 16 * nt] = (bf16)s[nt][r];

#pragma unroll
        for (int kc2 = 0; kc2 < 2; ++kc2) {
            bf16x8 pfr = *(const bf16x8*)&Pl[(wave * 16 + ln16) * LDT + kc2 * 32 + quad * 8];
#pragma unroll
            for (int dt = 0; dt < 4; ++dt) {
                bf16x8 vfr = *(const bf16x8*)&Vt[(ln16 + 16 * dt) * LDT + kc2 * 32 + quad * 8];
                o[dt] = __builtin_amdgcn_mfma_f32_16x16x32_bf16(pfr, vfr, o[dt], 0, 0, 0);
            }
        }
    }

#pragma unroll
    for (int r = 0; r < 4; ++r) {
        float inv = 1.0f / l_run[r];
        int qrow = q0 + wave * 16 + quad * 4 + r;
        float* orow = out + ((size_t)bh * SLEN + qrow) * DH;
#pragma unroll
        for (int dt = 0; dt < 4; ++dt)
            orow[ln16 + 16 * dt] = o[dt][r] * inv;
    }
}

extern "C" void kernel_launch(void* const* d_in, const int* in_sizes, int n_in,
                              void* d_out, int out_size, void* d_ws, size_t ws_size,
                              hipStream_t stream)
{
    const float* q    = (const float*)d_in[0];
    const float* kv   = (const float*)d_in[1];
    const float* mask = (const float*)d_in[2];
    float* out = (float*)d_out;

    const size_t kvKoff = 4096;                                   // flags: 32*32*4
    const size_t kvToff = kvKoff + (size_t)BH_N * NKT * IMGE_G * 2;
    const size_t need   = kvToff + (size_t)BH_N * NKT * IMGE_G * 2;

    if (ws_size >= need) {
        int*  flags = (int*)d_ws;
        bf16* kvK   = (bf16*)((char*)d_ws + kvKoff);
        bf16* kvT   = (bf16*)((char*)d_ws + kvToff);
        kv_prep<<<dim3(NKT, BH_N), 256, 0, stream>>>(kv, mask, kvK, kvT, flags);
        attn_fwd17<<<dim3(BH_N, SLEN / 128), 256, 0, stream>>>(q, mask, flags, kvK, kvT, out);
    } else {
        int* flags = nullptr;
        if (ws_size >= (size_t)NQT * NKT * sizeof(int)) {
            flags = (int*)d_ws;
            attn_mask_flags<<<dim3(NKT, NQT), 256, 0, stream>>>(mask, flags);
        }
        attn_fwd<<<dim3(NQT, BH_N), 256, 0, stream>>>(q, kv, mask, flags, out);
    }
}